// Round 4
// baseline (646.792 us; speedup 1.0000x reference)
//
#include <hip/hip_runtime.h>
#include <hip/hip_bf16.h>
#include <math.h>

#define N_NODES 2048
#define NEDGE   65536
#define FDIM    128
#define HDIM    512
#define EFD     16
#define EDD     64
#define LPATH   5
#define NLAYER  4
#define NHEAD   8
#define DK      64
#define ODIM    64
#define MAXDEG  64

typedef __bf16 bf16;
typedef bf16 bf16x8 __attribute__((ext_vector_type(8)));
typedef bf16 bf16x4 __attribute__((ext_vector_type(4)));
typedef float f32x4 __attribute__((ext_vector_type(4)));

// ---------------- small precompute kernels ----------------

__global__ void k_edge_mat(const float* __restrict__ W_edge, const float* __restrict__ b_edge,
                           const float* __restrict__ ev, float* __restrict__ M, float* __restrict__ c5) {
    int t = threadIdx.x;
    if (t < EFD * LPATH) {
        int i = t / LPATH, j = t % LPATH;
        float acc = 0.f;
        for (int k = 0; k < EDD; ++k) acc += W_edge[i * EDD + k] * ev[j * EDD + k];
        M[t] = acc;
    } else if (t >= 80 && t < 80 + LPATH) {
        int j = t - 80;
        float acc = 0.f;
        for (int k = 0; k < EDD; ++k) acc += b_edge[k] * ev[j * EDD + k];
        c5[j] = acc;
    }
}

__global__ __launch_bounds__(256) void k_edge_w(const float* __restrict__ ea, const float* __restrict__ M,
                                                const float* __restrict__ c5, float* __restrict__ w) {
    __shared__ float sM[80];
    __shared__ float sc[8];
    int t = threadIdx.x;
    if (t < 80) sM[t] = M[t];
    if (t < LPATH) sc[t] = c5[t];
    __syncthreads();
    int e = blockIdx.x * 256 + t;
    const float4* p = (const float4*)(ea + (size_t)e * EFD);
    float4 a0 = p[0], a1 = p[1], a2 = p[2], a3 = p[3];
    float a[16] = {a0.x, a0.y, a0.z, a0.w, a1.x, a1.y, a1.z, a1.w,
                   a2.x, a2.y, a2.z, a2.w, a3.x, a3.y, a3.z, a3.w};
    float out[LPATH];
#pragma unroll
    for (int j = 0; j < LPATH; ++j) out[j] = sc[j];
#pragma unroll
    for (int i = 0; i < 16; ++i)
#pragma unroll
        for (int j = 0; j < LPATH; ++j) out[j] += a[i] * sM[i * LPATH + j];
#pragma unroll
    for (int j = 0; j < LPATH; ++j) w[(size_t)e * LPATH + j] = out[j];
}

__global__ __launch_bounds__(256) void k_deg(const int* __restrict__ ei, int* __restrict__ din, int* __restrict__ dout) {
    int e = blockIdx.x * 256 + threadIdx.x;
    if (e < NEDGE) {
        atomicAdd(&dout[ei[e]], 1);
        atomicAdd(&din[ei[NEDGE + e]], 1);
    }
}

__global__ __launch_bounds__(256) void k_node_proj(const float* __restrict__ x, const float* __restrict__ Wn,
                                                   const float* __restrict__ bn, const float* __restrict__ zin,
                                                   const float* __restrict__ zout, const int* __restrict__ din,
                                                   const int* __restrict__ dout, float* __restrict__ h) {
    __shared__ float xs[FDIM];
    int i = blockIdx.x, t = threadIdx.x;
    if (t < FDIM) xs[t] = x[(size_t)i * FDIM + t];
    __syncthreads();
    int di = min(din[i], MAXDEG - 1), dz = min(dout[i], MAXDEG - 1);
    for (int j = t; j < HDIM; j += 256) {
        float acc = bn[j] + zin[(size_t)di * HDIM + j] + zout[(size_t)dz * HDIM + j];
        for (int k = 0; k < FDIM; ++k) acc += xs[k] * Wn[(size_t)k * HDIM + j];
        h[(size_t)i * HDIM + j] = acc;
    }
}

// ---------------- bias: plen == cnt (identical validity masks by construction) ----------------
__global__ __launch_bounds__(256) void k_bias(const int* __restrict__ ep, const float* __restrict__ w,
                                              const float* __restrict__ bsp, bf16* __restrict__ bias) {
    __shared__ float sb[5];
    int t = threadIdx.x;
    if (t < 5) sb[t] = bsp[t];
    __syncthreads();
    size_t tid = (size_t)blockIdx.x * 256 + t;
    const int4* p = (const int4*)(ep + tid * 20);
    int4 q0 = p[0], q1 = p[1], q2 = p[2], q3 = p[3], q4 = p[4];
    int e[20] = {q0.x, q0.y, q0.z, q0.w, q1.x, q1.y, q1.z, q1.w,
                 q2.x, q2.y, q2.z, q2.w, q3.x, q3.y, q3.z, q3.w,
                 q4.x, q4.y, q4.z, q4.w};
    bf16x4 out;
#pragma unroll
    for (int pp = 0; pp < 4; ++pp) {
        int cnt = 0;
        float cs = 0.f;
#pragma unroll
        for (int l = 0; l < LPATH; ++l) {
            int ev = e[pp * 5 + l];
            if (ev >= 0) { cnt++; cs += w[(size_t)ev * LPATH + l]; }
        }
        float b = (cnt > 0) ? sb[cnt - 1] + cs / (float)cnt : 0.f;
        out[pp] = (bf16)b;
    }
    *(bf16x4*)(bias + tid * 4) = out;
}

// ---------------- layernorm: f32 in, bf16 out ----------------
__global__ __launch_bounds__(256) void k_ln(const float* __restrict__ h, const float* __restrict__ sc,
                                            const float* __restrict__ bi, bf16* __restrict__ y) {
    int i = blockIdx.x, t = threadIdx.x;
    float v0 = h[(size_t)i * HDIM + t];
    float v1 = h[(size_t)i * HDIM + 256 + t];
    float s = v0 + v1, q = v0 * v0 + v1 * v1;
#pragma unroll
    for (int m = 1; m < 64; m <<= 1) { s += __shfl_xor(s, m); q += __shfl_xor(q, m); }
    __shared__ float ssum[4], sq[4];
    int wv = t >> 6;
    if ((t & 63) == 0) { ssum[wv] = s; sq[wv] = q; }
    __syncthreads();
    float S = ssum[0] + ssum[1] + ssum[2] + ssum[3];
    float Q = sq[0] + sq[1] + sq[2] + sq[3];
    float mean = S * (1.f / HDIM);
    float var = Q * (1.f / HDIM) - mean * mean;
    float r = rsqrtf(var + 1e-5f);
    y[(size_t)i * HDIM + t] = (bf16)((v0 - mean) * r * sc[t] + bi[t]);
    y[(size_t)i * HDIM + 256 + t] = (bf16)((v1 - mean) * r * sc[256 + t] + bi[256 + t]);
}

// ---------------- weight prep: f32 [K][N] -> bf16 W^T [N][K] ----------------
__global__ __launch_bounds__(256) void k_wprep(const float* __restrict__ Wq, const float* __restrict__ Wk,
                                               const float* __restrict__ Wv, const float* __restrict__ Wo,
                                               const float* __restrict__ W1, const float* __restrict__ W2,
                                               bf16* __restrict__ Wt) {
    __shared__ float Ls[64][68];
    int m = blockIdx.y;
    int lay = m / 6, type = m % 6;
    const float* src = type == 0 ? Wq : type == 1 ? Wk : type == 2 ? Wv : type == 3 ? Wo : type == 4 ? W1 : W2;
    src += (size_t)lay * (HDIM * HDIM);
    int q = blockIdx.x;
    int tk = q >> 3, tn = q & 7;
    int t = threadIdx.x;
    int rr = t >> 4, cc = t & 15;
#pragma unroll
    for (int u = 0; u < 4; ++u) {
        float4 v = *(const float4*)(src + (size_t)(tk * 64 + rr + 16 * u) * HDIM + tn * 64 + cc * 4);
        *(float4*)&Ls[rr + 16 * u][cc * 4] = v;
    }
    __syncthreads();
    int nl = t >> 2, kc = t & 3;
    bf16 tmp[16];
#pragma unroll
    for (int u = 0; u < 16; ++u) tmp[u] = (bf16)Ls[kc * 16 + u][nl];
    bf16* dst = Wt + (size_t)m * (HDIM * HDIM) + (size_t)(tn * 64 + nl) * HDIM + tk * 64 + kc * 16;
    *(bf16x8*)(dst) = *(bf16x8*)&tmp[0];
    *(bf16x8*)(dst + 8) = *(bf16x8*)&tmp[8];
}

// ---------------- fused QKV GEMM (bf16 MFMA), LDS-staged B panel ----------------
__global__ __launch_bounds__(256) void k_qkv(const bf16* __restrict__ A, const bf16* __restrict__ Wt_l,
                                             const float* __restrict__ bq, const float* __restrict__ bk,
                                             const float* __restrict__ bv, bf16* __restrict__ qk,
                                             bf16* __restrict__ vt) {
    __shared__ bf16 Bs[16384];   // 32 n-rows x 512 K, frag-contiguous
    __shared__ bf16 Tr[32][72];
    int t = threadIdx.x, w = t >> 6, l = t & 63, lr = l & 15, lg = l >> 4;
    int j0 = blockIdx.x * 32, i0 = blockIdx.y * 64;
    int type = j0 >> 9, n0 = j0 & 511;
    const bf16* Bp = Wt_l + (size_t)type * (HDIM * HDIM) + (size_t)n0 * HDIM;
#pragma unroll
    for (int rnd = 0; rnd < 8; ++rnd) {
        int tt = rnd * 256 + t;
        int ks = tt >> 7, qq = (tt >> 6) & 1, mm = (tt >> 2) & 15, gg = tt & 3;
        bf16x8 v = *(const bf16x8*)(Bp + (size_t)(qq * 16 + mm) * HDIM + ks * 32 + gg * 8);
        *(bf16x8*)(Bs + tt * 8) = v;
    }
    __syncthreads();
    const bf16* ap = A + (size_t)(i0 + w * 16 + lr) * HDIM + 8 * lg;
    const float* bvec = (type == 0 ? bq : type == 1 ? bk : bv);
    f32x4 acc[2] = {};
#pragma unroll 4
    for (int ks = 0; ks < 16; ++ks) {
        bf16x8 a  = *(const bf16x8*)(ap + ks * 32);
        const bf16* bb = Bs + ks * 1024 + lr * 32 + lg * 8;
        bf16x8 b0 = *(const bf16x8*)(bb);
        bf16x8 b1 = *(const bf16x8*)(bb + 512);
        acc[0] = __builtin_amdgcn_mfma_f32_16x16x32_bf16(a, b0, acc[0], 0, 0, 0);
        acc[1] = __builtin_amdgcn_mfma_f32_16x16x32_bf16(a, b1, acc[1], 0, 0, 0);
    }
    if (type < 2) {
        int head = n0 >> 6;
#pragma unroll
        for (int sub = 0; sub < 2; ++sub) {
#pragma unroll
            for (int r = 0; r < 4; ++r) {
                int i = i0 + w * 16 + lg * 4 + r;
                int n = n0 + sub * 16 + lr;
                float v = acc[sub][r] + bvec[n];
                qk[((size_t)(type * NHEAD + head) * N_NODES + i) * DK + (n & 63)] = (bf16)v;
            }
        }
    } else {
#pragma unroll
        for (int sub = 0; sub < 2; ++sub) {
#pragma unroll
            for (int r = 0; r < 4; ++r) {
                int il = w * 16 + lg * 4 + r;
                int cl = sub * 16 + lr;
                float v = acc[sub][r] + bvec[n0 + cl];
                Tr[cl][il] = (bf16)v;
            }
        }
        __syncthreads();
        int dl = t >> 3, ic = (t & 7) * 8;
        bf16x8 row = *(bf16x8*)&Tr[dl][ic];
        *(bf16x8*)(vt + (size_t)(n0 + dl) * N_NODES + i0 + ic) = row;
    }
}

// ---------------- generic bf16 MFMA GEMM, BN=64, 16 waves, 4-way K-split ----------------
#define FL_RES   1
#define FL_GELU  2
#define FL_OUTF  4

__device__ inline float gelu_f(float x) {
    float x3 = x * x * x;
    float u = 0.7978845608028654f * (x + 0.044715f * x3);
    return 0.5f * x * (1.f + tanhf(u));
}

__global__ __launch_bounds__(1024) void k_mm(const bf16* __restrict__ A, const bf16* __restrict__ Bt,
                                             const float* __restrict__ bvec, const float* __restrict__ res,
                                             float* __restrict__ outF, bf16* __restrict__ outB, int flags) {
    __shared__ bf16 Bs[32768];        // 64 n-rows x 512 K, frag-contiguous (64 KB)
    __shared__ float Osh[4][16][68];  // padded partial-sum buffer
    int t = threadIdx.x, w = t >> 6, l = t & 63, lr = l & 15, lg = l >> 4;
    int ti = w & 3, s = w >> 2;
    int j0 = blockIdx.x * 64, i0 = blockIdx.y * 64;
    const bf16* Bp = Bt + (size_t)j0 * HDIM;
#pragma unroll
    for (int rnd = 0; rnd < 4; ++rnd) {
        int tt = rnd * 1024 + t;
        int ks = tt >> 8, qq = (tt >> 6) & 3, mm = (tt >> 2) & 15, gg = tt & 3;
        bf16x8 v = *(const bf16x8*)(Bp + (size_t)(qq * 16 + mm) * HDIM + ks * 32 + gg * 8);
        *(bf16x8*)(Bs + tt * 8) = v;
    }
    __syncthreads();
    const bf16* ap = A + (size_t)(i0 + ti * 16 + lr) * HDIM + 8 * lg;
    f32x4 acc[4] = {};
#pragma unroll
    for (int kk = 0; kk < 4; ++kk) {
        int ks = s * 4 + kk;
        bf16x8 a = *(const bf16x8*)(ap + ks * 32);
        const bf16* bb = Bs + ks * 2048 + lr * 32 + lg * 8;
#pragma unroll
        for (int sub = 0; sub < 4; ++sub) {
            bf16x8 b = *(const bf16x8*)(bb + sub * 512);
            acc[sub] = __builtin_amdgcn_mfma_f32_16x16x32_bf16(a, b, acc[sub], 0, 0, 0);
        }
    }
    // merge K-split partials
    if (s == 0) {
#pragma unroll
        for (int sub = 0; sub < 4; ++sub)
#pragma unroll
            for (int r = 0; r < 4; ++r) Osh[ti][lg * 4 + r][sub * 16 + lr] = acc[sub][r];
    }
    __syncthreads();
    if (s == 1) {
#pragma unroll
        for (int sub = 0; sub < 4; ++sub)
#pragma unroll
            for (int r = 0; r < 4; ++r) Osh[ti][lg * 4 + r][sub * 16 + lr] += acc[sub][r];
    }
    __syncthreads();
    if (s == 2) {
#pragma unroll
        for (int sub = 0; sub < 4; ++sub)
#pragma unroll
            for (int r = 0; r < 4; ++r) Osh[ti][lg * 4 + r][sub * 16 + lr] += acc[sub][r];
    }
    __syncthreads();
    if (s == 3) {
#pragma unroll
        for (int sub = 0; sub < 4; ++sub) {
#pragma unroll
            for (int r = 0; r < 4; ++r) {
                int i = i0 + ti * 16 + lg * 4 + r;
                int j = j0 + sub * 16 + lr;
                float v = Osh[ti][lg * 4 + r][sub * 16 + lr] + acc[sub][r] + bvec[j];
                if (flags & FL_RES) v += res[(size_t)i * HDIM + j];
                if (flags & FL_GELU) v = gelu_f(v);
                if (flags & FL_OUTF) outF[(size_t)i * HDIM + j] = v;
                else outB[(size_t)i * HDIM + j] = (bf16)v;
            }
        }
    }
}

// ---------------- MFMA flash attention: 16 waves, 4-way j-split + in-block merge ----------------
__global__ __launch_bounds__(1024) void k_attn_mfma(const bf16* __restrict__ qk, const bf16* __restrict__ vt,
                                                    const bf16* __restrict__ biasb, bf16* __restrict__ ob) {
    __shared__ unsigned char Pb[16 * 2048];  // per-wave 16x64 bf16 P tile, XOR-swizzled (32 KB)
    __shared__ float Osh[4][16][68];         // merge buffer
    __shared__ float Msh[4][4][16];
    __shared__ float Lsh[4][4][16];
    int t = threadIdx.x, w = t >> 6, l = t & 63, lr = l & 15, lg = l >> 4;
    int ti = w & 3, s = w >> 2;
    int bid = blockIdx.x;
    int wid = (bid & 7) * 32 + (bid >> 3);  // XCD-chunk: 4 i-tiles x 8 heads per XCD
    int i0 = (wid >> 3) * 64;
    int hh = wid & 7;
    int irow = i0 + ti * 16;
    unsigned wbase = (unsigned)w * 2048;

    const bf16* qbase = qk + ((size_t)hh * N_NODES + irow + lr) * DK;
    bf16x8 qa0 = *(const bf16x8*)(qbase + 8 * lg);
    bf16x8 qa1 = *(const bf16x8*)(qbase + 32 + 8 * lg);
    const bf16* kbase = qk + (size_t)(NHEAD + hh) * N_NODES * DK;
    const bf16* vbase = vt + (size_t)hh * DK * N_NODES;

    float m_run[4] = {-1e30f, -1e30f, -1e30f, -1e30f};
    float l_run[4] = {0.f, 0.f, 0.f, 0.f};
    f32x4 oacc[4] = {};

    for (int jj = 0; jj < (N_NODES / 4) / 64; ++jj) {
        int j0 = s * (N_NODES / 4) + jj * 64;
        bf16x8 kb0[4], kb1[4], vb0[4], vb1[4];
        float bvals[4][4];
#pragma unroll
        for (int sub = 0; sub < 4; ++sub) {
            const bf16* kp = kbase + (size_t)(j0 + sub * 16 + lr) * DK + 8 * lg;
            kb0[sub] = *(const bf16x8*)(kp);
            kb1[sub] = *(const bf16x8*)(kp + 32);
            const bf16* vp = vbase + (size_t)(sub * 16 + lr) * N_NODES + j0 + 8 * lg;
            vb0[sub] = *(const bf16x8*)(vp);
            vb1[sub] = *(const bf16x8*)(vp + 32);
#pragma unroll
            for (int r = 0; r < 4; ++r)
                bvals[sub][r] = (float)biasb[(size_t)(irow + lg * 4 + r) * N_NODES + j0 + sub * 16 + lr];
        }
        f32x4 sc[4] = {};
#pragma unroll
        for (int sub = 0; sub < 4; ++sub) {
            sc[sub] = __builtin_amdgcn_mfma_f32_16x16x32_bf16(qa0, kb0[sub], sc[sub], 0, 0, 0);
            sc[sub] = __builtin_amdgcn_mfma_f32_16x16x32_bf16(qa1, kb1[sub], sc[sub], 0, 0, 0);
        }
        float mt[4];
#pragma unroll
        for (int r = 0; r < 4; ++r) {
            float v0 = sc[0][r] * 0.125f + bvals[0][r];
            float v1 = sc[1][r] * 0.125f + bvals[1][r];
            float v2 = sc[2][r] * 0.125f + bvals[2][r];
            float v3 = sc[3][r] * 0.125f + bvals[3][r];
            sc[0][r] = v0; sc[1][r] = v1; sc[2][r] = v2; sc[3][r] = v3;
            mt[r] = fmaxf(fmaxf(v0, v1), fmaxf(v2, v3));
        }
#pragma unroll
        for (int mk = 1; mk < 16; mk <<= 1) {
#pragma unroll
            for (int r = 0; r < 4; ++r) mt[r] = fmaxf(mt[r], __shfl_xor(mt[r], mk));
        }
        float alpha[4], psum[4];
#pragma unroll
        for (int r = 0; r < 4; ++r) {
            float mn = fmaxf(m_run[r], mt[r]);
            alpha[r] = __expf(m_run[r] - mn);
            m_run[r] = mn;
            psum[r] = 0.f;
        }
#pragma unroll
        for (int sub = 0; sub < 4; ++sub) {
#pragma unroll
            for (int r = 0; r < 4; ++r) {
                float p = __expf(sc[sub][r] - m_run[r]);
                psum[r] += p;
                int row = lg * 4 + r;
                unsigned addr = wbase + (((unsigned)(row * 128 + (sub * 16 + lr) * 2)) ^ ((row & 7) << 4));
                *(bf16*)(&Pb[addr]) = (bf16)p;
            }
        }
#pragma unroll
        for (int mk = 1; mk < 16; mk <<= 1) {
#pragma unroll
            for (int r = 0; r < 4; ++r) psum[r] += __shfl_xor(psum[r], mk);
        }
#pragma unroll
        for (int r = 0; r < 4; ++r) l_run[r] = l_run[r] * alpha[r] + psum[r];
#pragma unroll
        for (int d = 0; d < 4; ++d)
#pragma unroll
            for (int r = 0; r < 4; ++r) oacc[d][r] *= alpha[r];
        asm volatile("s_waitcnt lgkmcnt(0)" ::: "memory");
        __builtin_amdgcn_sched_barrier(0);
        unsigned ra0 = wbase + (((unsigned)(lr * 128 + 16 * lg)) ^ ((lr & 7) << 4));
        unsigned ra1 = wbase + (((unsigned)(lr * 128 + 64 + 16 * lg)) ^ ((lr & 7) << 4));
        bf16x8 pa0 = *(bf16x8*)(&Pb[ra0]);
        bf16x8 pa1 = *(bf16x8*)(&Pb[ra1]);
#pragma unroll
        for (int d = 0; d < 4; ++d) {
            oacc[d] = __builtin_amdgcn_mfma_f32_16x16x32_bf16(pa0, vb0[d], oacc[d], 0, 0, 0);
            oacc[d] = __builtin_amdgcn_mfma_f32_16x16x32_bf16(pa1, vb1[d], oacc[d], 0, 0, 0);
        }
    }
    // ---- merge 4 j-splits ----
    __syncthreads();
    if (lr == 0) {
#pragma unroll
        for (int r = 0; r < 4; ++r) { Msh[ti][s][lg * 4 + r] = m_run[r]; Lsh[ti][s][lg * 4 + r] = l_run[r]; }
    }
    __syncthreads();
    float fac[4], l_tot[4];
#pragma unroll
    for (int r = 0; r < 4; ++r) {
        int row = lg * 4 + r;
        float m0 = Msh[ti][0][row], m1 = Msh[ti][1][row], m2 = Msh[ti][2][row], m3 = Msh[ti][3][row];
        float mtot = fmaxf(fmaxf(m0, m1), fmaxf(m2, m3));
        l_tot[r] = Lsh[ti][0][row] * __expf(m0 - mtot) + Lsh[ti][1][row] * __expf(m1 - mtot)
                 + Lsh[ti][2][row] * __expf(m2 - mtot) + Lsh[ti][3][row] * __expf(m3 - mtot);
        fac[r] = __expf(m_run[r] - mtot);
    }
#pragma unroll
    for (int d = 0; d < 4; ++d)
#pragma unroll
        for (int r = 0; r < 4; ++r) oacc[d][r] *= fac[r];
    if (s == 0) {
#pragma unroll
        for (int d = 0; d < 4; ++d)
#pragma unroll
            for (int r = 0; r < 4; ++r) Osh[ti][lg * 4 + r][d * 16 + lr] = oacc[d][r];
    }
    __syncthreads();
    if (s == 1) {
#pragma unroll
        for (int d = 0; d < 4; ++d)
#pragma unroll
            for (int r = 0; r < 4; ++r) Osh[ti][lg * 4 + r][d * 16 + lr] += oacc[d][r];
    }
    __syncthreads();
    if (s == 2) {
#pragma unroll
        for (int d = 0; d < 4; ++d)
#pragma unroll
            for (int r = 0; r < 4; ++r) Osh[ti][lg * 4 + r][d * 16 + lr] += oacc[d][r];
    }
    __syncthreads();
    if (s == 3) {
#pragma unroll
        for (int r = 0; r < 4; ++r) {
            float inv = 1.f / l_tot[r];
            int i = irow + lg * 4 + r;
            bf16* op = ob + (size_t)i * HDIM + hh * DK + lr;
#pragma unroll
            for (int d = 0; d < 4; ++d)
                op[d * 16] = (bf16)((Osh[ti][lg * 4 + r][d * 16 + lr] + oacc[d][r]) * inv);
        }
    }
}

// ---------------- f32 GEMM (final 512->64 projection only) ----------------
__global__ __launch_bounds__(256) void k_gemm(const float* __restrict__ A, const float* __restrict__ B,
                                              const float* __restrict__ bvec, float* __restrict__ C,
                                              int M, int Nc, int K) {
    __shared__ float As[16][68];
    __shared__ float Bs[16][68];
    int t = threadIdx.x;
    int tm = t >> 4, tn = t & 15;
    int i0 = blockIdx.y * 64, j0 = blockIdx.x * 64;
    int ar = t >> 2, aq = t & 3;
    int br = t >> 4, bq = t & 15;
    float acc[4][4] = {};
    for (int k0 = 0; k0 < K; k0 += 16) {
        float4 av = *(const float4*)(A + (size_t)(i0 + ar) * K + k0 + aq * 4);
        As[aq * 4 + 0][ar] = av.x;
        As[aq * 4 + 1][ar] = av.y;
        As[aq * 4 + 2][ar] = av.z;
        As[aq * 4 + 3][ar] = av.w;
        *(float4*)&Bs[br][bq * 4] = *(const float4*)(B + (size_t)(k0 + br) * Nc + j0 + bq * 4);
        __syncthreads();
#pragma unroll
        for (int k = 0; k < 16; ++k) {
            float4 a4 = *(const float4*)&As[k][tm * 4];
            float4 b4 = *(const float4*)&Bs[k][tn * 4];
            float avv[4] = {a4.x, a4.y, a4.z, a4.w};
            float bvv[4] = {b4.x, b4.y, b4.z, b4.w};
#pragma unroll
            for (int r = 0; r < 4; ++r)
#pragma unroll
                for (int c = 0; c < 4; ++c) acc[r][c] += avv[r] * bvv[c];
        }
        __syncthreads();
    }
#pragma unroll
    for (int r = 0; r < 4; ++r) {
#pragma unroll
        for (int c = 0; c < 4; ++c) {
            int i = i0 + tm * 4 + r;
            int j = j0 + tn * 4 + c;
            C[(size_t)i * Nc + j] = acc[r][c] + bvec[j];
        }
    }
}

extern "C" void kernel_launch(void* const* d_in, const int* in_sizes, int n_in,
                              void* d_out, int out_size, void* d_ws, size_t ws_size,
                              hipStream_t stream) {
    const float* x      = (const float*)d_in[0];
    const int*   ei     = (const int*)d_in[1];
    const float* eattr  = (const float*)d_in[2];
    const int*   epaths = (const int*)d_in[4];
    const float* Wn     = (const float*)d_in[5];
    const float* bn     = (const float*)d_in[6];
    const float* We     = (const float*)d_in[7];
    const float* be     = (const float*)d_in[8];
    const float* zin    = (const float*)d_in[9];
    const float* zout   = (const float*)d_in[10];
    const float* bsp    = (const float*)d_in[11];
    const float* ev     = (const float*)d_in[12];
    const float* ln1s   = (const float*)d_in[13];
    const float* ln1b   = (const float*)d_in[14];
    const float* Wq     = (const float*)d_in[15];
    const float* bq     = (const float*)d_in[16];
    const float* Wk     = (const float*)d_in[17];
    const float* bk     = (const float*)d_in[18];
    const float* Wv     = (const float*)d_in[19];
    const float* bv     = (const float*)d_in[20];
    const float* Wo     = (const float*)d_in[21];
    const float* bo     = (const float*)d_in[22];
    const float* ln2s   = (const float*)d_in[23];
    const float* ln2b   = (const float*)d_in[24];
    const float* W1     = (const float*)d_in[25];
    const float* b1     = (const float*)d_in[26];
    const float* W2     = (const float*)d_in[27];
    const float* b2     = (const float*)d_in[28];
    const float* Wout   = (const float*)d_in[29];
    const float* bout   = (const float*)d_in[30];

    char* base = (char*)d_ws;
    size_t off = 0;
    auto alloc = [&](size_t bytes) { char* p = base + off; off = (off + bytes + 255) & ~(size_t)255; return p; };
    bf16*  bias   = (bf16*)alloc((size_t)N_NODES * N_NODES * 2);
    float* h      = (float*)alloc((size_t)N_NODES * HDIM * 4);
    float* wbuf   = (float*)alloc((size_t)NEDGE * LPATH * 4);
    float* Mb     = (float*)alloc(96 * 4);
    float* c5     = (float*)alloc(16 * 4);
    int*   deg    = (int*)alloc(2 * N_NODES * 4);
    bf16*  y_bf   = (bf16*)alloc((size_t)N_NODES * HDIM * 2);
    bf16*  qkt    = (bf16*)alloc((size_t)2 * NHEAD * N_NODES * DK * 2);
    bf16*  vt     = (bf16*)alloc((size_t)HDIM * N_NODES * 2);
    bf16*  ob_bf  = (bf16*)alloc((size_t)N_NODES * HDIM * 2);
    bf16*  t1_bf  = (bf16*)alloc((size_t)N_NODES * HDIM * 2);
    bf16*  Wt     = (bf16*)alloc((size_t)NLAYER * 6 * HDIM * HDIM * 2);
    int* din = deg;
    int* dout = deg + N_NODES;

    hipMemsetAsync(deg, 0, 2 * N_NODES * sizeof(int), stream);

    k_edge_mat<<<1, 128, 0, stream>>>(We, be, ev, Mb, c5);
    k_edge_w<<<NEDGE / 256, 256, 0, stream>>>(eattr, Mb, c5, wbuf);
    k_deg<<<NEDGE / 256, 256, 0, stream>>>(ei, din, dout);
    k_node_proj<<<N_NODES, 256, 0, stream>>>(x, Wn, bn, zin, zout, din, dout, h);
    k_bias<<<(N_NODES * (size_t)N_NODES) / 1024, 256, 0, stream>>>(epaths, wbuf, bsp, bias);
    k_wprep<<<dim3(64, 24), 256, 0, stream>>>(Wq, Wk, Wv, Wo, W1, W2, Wt);

    dim3 gqkv(48, 32);
    dim3 gmm(8, 32);

    for (int l = 0; l < NLAYER; ++l) {
        const bf16* Wt_l = Wt + (size_t)l * 6 * HDIM * HDIM;
        size_t bOff = (size_t)l * HDIM;
        k_ln<<<N_NODES, 256, 0, stream>>>(h, ln1s + bOff, ln1b + bOff, y_bf);
        k_qkv<<<gqkv, 256, 0, stream>>>(y_bf, Wt_l, bq + bOff, bk + bOff, bv + bOff, qkt, vt);
        k_attn_mfma<<<256, 1024, 0, stream>>>(qkt, vt, bias, ob_bf);
        k_mm<<<gmm, 1024, 0, stream>>>(ob_bf, Wt_l + (size_t)3 * HDIM * HDIM, bo + bOff, h, h, nullptr, FL_RES | FL_OUTF);
        k_ln<<<N_NODES, 256, 0, stream>>>(h, ln2s + bOff, ln2b + bOff, y_bf);
        k_mm<<<gmm, 1024, 0, stream>>>(y_bf, Wt_l + (size_t)4 * HDIM * HDIM, b1 + bOff, nullptr, nullptr, t1_bf, FL_GELU);
        k_mm<<<gmm, 1024, 0, stream>>>(t1_bf, Wt_l + (size_t)5 * HDIM * HDIM, b2 + bOff, h, h, nullptr, FL_RES | FL_OUTF);
    }
    k_gemm<<<dim3(1, 32), 256, 0, stream>>>(h, Wout, bout, (float*)d_out, N_NODES, ODIM, HDIM);
}

// Round 5
// 505.835 us; speedup vs baseline: 1.2787x; 1.2787x over previous
//
#include <hip/hip_runtime.h>
#include <hip/hip_bf16.h>
#include <math.h>

#define N_NODES 2048
#define NEDGE   65536
#define FDIM    128
#define HDIM    512
#define EFD     16
#define EDD     64
#define LPATH   5
#define NLAYER  4
#define NHEAD   8
#define DK      64
#define ODIM    64
#define MAXDEG  64

typedef __bf16 bf16;
typedef bf16 bf16x8 __attribute__((ext_vector_type(8)));
typedef bf16 bf16x4 __attribute__((ext_vector_type(4)));
typedef float f32x4 __attribute__((ext_vector_type(4)));

// ---------------- small precompute kernels ----------------

__global__ void k_edge_mat(const float* __restrict__ W_edge, const float* __restrict__ b_edge,
                           const float* __restrict__ ev, float* __restrict__ M, float* __restrict__ c5) {
    int t = threadIdx.x;
    if (t < EFD * LPATH) {
        int i = t / LPATH, j = t % LPATH;
        float acc = 0.f;
        for (int k = 0; k < EDD; ++k) acc += W_edge[i * EDD + k] * ev[j * EDD + k];
        M[t] = acc;
    } else if (t >= 80 && t < 80 + LPATH) {
        int j = t - 80;
        float acc = 0.f;
        for (int k = 0; k < EDD; ++k) acc += b_edge[k] * ev[j * EDD + k];
        c5[j] = acc;
    }
}

__global__ __launch_bounds__(256) void k_edge_w(const float* __restrict__ ea, const float* __restrict__ M,
                                                const float* __restrict__ c5, bf16* __restrict__ w) {
    __shared__ float sM[80];
    __shared__ float sc[8];
    int t = threadIdx.x;
    if (t < 80) sM[t] = M[t];
    if (t < LPATH) sc[t] = c5[t];
    __syncthreads();
    int e = blockIdx.x * 256 + t;
    const float4* p = (const float4*)(ea + (size_t)e * EFD);
    float4 a0 = p[0], a1 = p[1], a2 = p[2], a3 = p[3];
    float a[16] = {a0.x, a0.y, a0.z, a0.w, a1.x, a1.y, a1.z, a1.w,
                   a2.x, a2.y, a2.z, a2.w, a3.x, a3.y, a3.z, a3.w};
    float out[LPATH];
#pragma unroll
    for (int j = 0; j < LPATH; ++j) out[j] = sc[j];
#pragma unroll
    for (int i = 0; i < 16; ++i)
#pragma unroll
        for (int j = 0; j < LPATH; ++j) out[j] += a[i] * sM[i * LPATH + j];
#pragma unroll
    for (int j = 0; j < LPATH; ++j) w[(size_t)e * LPATH + j] = (bf16)out[j];
}

__global__ __launch_bounds__(256) void k_deg(const int* __restrict__ ei, int* __restrict__ din, int* __restrict__ dout) {
    int e = blockIdx.x * 256 + threadIdx.x;
    if (e < NEDGE) {
        atomicAdd(&dout[ei[e]], 1);
        atomicAdd(&din[ei[NEDGE + e]], 1);
    }
}

__global__ __launch_bounds__(256) void k_node_proj(const float* __restrict__ x, const float* __restrict__ Wn,
                                                   const float* __restrict__ bn, const float* __restrict__ zin,
                                                   const float* __restrict__ zout, const int* __restrict__ din,
                                                   const int* __restrict__ dout, float* __restrict__ h) {
    __shared__ float xs[FDIM];
    int i = blockIdx.x, t = threadIdx.x;
    if (t < FDIM) xs[t] = x[(size_t)i * FDIM + t];
    __syncthreads();
    int di = min(din[i], MAXDEG - 1), dz = min(dout[i], MAXDEG - 1);
    for (int j = t; j < HDIM; j += 256) {
        float acc = bn[j] + zin[(size_t)di * HDIM + j] + zout[(size_t)dz * HDIM + j];
        for (int k = 0; k < FDIM; ++k) acc += xs[k] * Wn[(size_t)k * HDIM + j];
        h[(size_t)i * HDIM + j] = acc;
    }
}

// ---------------- bias: plen == cnt (identical validity masks by construction) ----------------
__global__ __launch_bounds__(256) void k_bias(const int* __restrict__ ep, const bf16* __restrict__ w,
                                              const float* __restrict__ bsp, bf16* __restrict__ bias) {
    __shared__ float sb[5];
    int t = threadIdx.x;
    if (t < 5) sb[t] = bsp[t];
    __syncthreads();
    size_t tid = (size_t)blockIdx.x * 256 + t;
    const int4* p = (const int4*)(ep + tid * 20);
    int4 q0 = p[0], q1 = p[1], q2 = p[2], q3 = p[3], q4 = p[4];
    int e[20] = {q0.x, q0.y, q0.z, q0.w, q1.x, q1.y, q1.z, q1.w,
                 q2.x, q2.y, q2.z, q2.w, q3.x, q3.y, q3.z, q3.w,
                 q4.x, q4.y, q4.z, q4.w};
    bf16x4 out;
#pragma unroll
    for (int pp = 0; pp < 4; ++pp) {
        int cnt = 0;
        float cs = 0.f;
#pragma unroll
        for (int l = 0; l < LPATH; ++l) {
            int ev = e[pp * 5 + l];
            if (ev >= 0) { cnt++; cs += (float)w[(size_t)ev * LPATH + l]; }
        }
        float b = (cnt > 0) ? sb[cnt - 1] + cs / (float)cnt : 0.f;
        out[pp] = (bf16)b;
    }
    *(bf16x4*)(bias + tid * 4) = out;
}

// ---------------- layernorm: f32 in, bf16 out ----------------
__global__ __launch_bounds__(256) void k_ln(const float* __restrict__ h, const float* __restrict__ sc,
                                            const float* __restrict__ bi, bf16* __restrict__ y) {
    int i = blockIdx.x, t = threadIdx.x;
    float v0 = h[(size_t)i * HDIM + t];
    float v1 = h[(size_t)i * HDIM + 256 + t];
    float s = v0 + v1, q = v0 * v0 + v1 * v1;
#pragma unroll
    for (int m = 1; m < 64; m <<= 1) { s += __shfl_xor(s, m); q += __shfl_xor(q, m); }
    __shared__ float ssum[4], sq[4];
    int wv = t >> 6;
    if ((t & 63) == 0) { ssum[wv] = s; sq[wv] = q; }
    __syncthreads();
    float S = ssum[0] + ssum[1] + ssum[2] + ssum[3];
    float Q = sq[0] + sq[1] + sq[2] + sq[3];
    float mean = S * (1.f / HDIM);
    float var = Q * (1.f / HDIM) - mean * mean;
    float r = rsqrtf(var + 1e-5f);
    y[(size_t)i * HDIM + t] = (bf16)((v0 - mean) * r * sc[t] + bi[t]);
    y[(size_t)i * HDIM + 256 + t] = (bf16)((v1 - mean) * r * sc[256 + t] + bi[256 + t]);
}

// ---------------- weight prep: f32 [K][N] -> bf16 W^T [N][K] ----------------
__global__ __launch_bounds__(256) void k_wprep(const float* __restrict__ Wq, const float* __restrict__ Wk,
                                               const float* __restrict__ Wv, const float* __restrict__ Wo,
                                               const float* __restrict__ W1, const float* __restrict__ W2,
                                               bf16* __restrict__ Wt) {
    __shared__ float Ls[64][68];
    int m = blockIdx.y;
    int lay = m / 6, type = m % 6;
    const float* src = type == 0 ? Wq : type == 1 ? Wk : type == 2 ? Wv : type == 3 ? Wo : type == 4 ? W1 : W2;
    src += (size_t)lay * (HDIM * HDIM);
    int q = blockIdx.x;
    int tk = q >> 3, tn = q & 7;
    int t = threadIdx.x;
    int rr = t >> 4, cc = t & 15;
#pragma unroll
    for (int u = 0; u < 4; ++u) {
        float4 v = *(const float4*)(src + (size_t)(tk * 64 + rr + 16 * u) * HDIM + tn * 64 + cc * 4);
        *(float4*)&Ls[rr + 16 * u][cc * 4] = v;
    }
    __syncthreads();
    int nl = t >> 2, kc = t & 3;
    bf16 tmp[16];
#pragma unroll
    for (int u = 0; u < 16; ++u) tmp[u] = (bf16)Ls[kc * 16 + u][nl];
    bf16* dst = Wt + (size_t)m * (HDIM * HDIM) + (size_t)(tn * 64 + nl) * HDIM + tk * 64 + kc * 16;
    *(bf16x8*)(dst) = *(bf16x8*)&tmp[0];
    *(bf16x8*)(dst + 8) = *(bf16x8*)&tmp[8];
}

// ---------------- fused QKV GEMM -> frag-contiguous q/k/v layouts ----------------
// qf/kf: per (head, node-tile16, khalf): 64 lanes x 8 bf16; element[lg][lr][e] = X[jt*16+lr][hf*32+lg*8+e]
// vf:    per (head, dblock16, node-tile32): element[lg][lr][e] = V[jt32*32+lg*8+e][db*16+lr]
__global__ __launch_bounds__(256) void k_qkv(const bf16* __restrict__ A, const bf16* __restrict__ Wt_l,
                                             const float* __restrict__ bq, const float* __restrict__ bk,
                                             const float* __restrict__ bv, bf16* __restrict__ qf,
                                             bf16* __restrict__ kf, bf16* __restrict__ vf) {
    __shared__ bf16 Bs[16384];   // 32 n-rows x 512 K, frag-contiguous
    int t = threadIdx.x, w = t >> 6, l = t & 63, lr = l & 15, lg = l >> 4;
    int j0 = blockIdx.x * 32, i0 = blockIdx.y * 64;
    int type = j0 >> 9, n0 = j0 & 511;
    const bf16* Bp = Wt_l + (size_t)type * (HDIM * HDIM) + (size_t)n0 * HDIM;
#pragma unroll
    for (int rnd = 0; rnd < 8; ++rnd) {
        int tt = rnd * 256 + t;
        int ks = tt >> 7, qq = (tt >> 6) & 1, mm = (tt >> 2) & 15, gg = tt & 3;
        bf16x8 v = *(const bf16x8*)(Bp + (size_t)(qq * 16 + mm) * HDIM + ks * 32 + gg * 8);
        *(bf16x8*)(Bs + tt * 8) = v;
    }
    __syncthreads();
    const bf16* ap = A + (size_t)(i0 + w * 16 + lr) * HDIM + 8 * lg;
    const float* bvec = (type == 0 ? bq : type == 1 ? bk : bv);
    f32x4 acc[2] = {};
#pragma unroll 4
    for (int ks = 0; ks < 16; ++ks) {
        bf16x8 a  = *(const bf16x8*)(ap + ks * 32);
        const bf16* bb = Bs + ks * 1024 + lr * 32 + lg * 8;
        bf16x8 b0 = *(const bf16x8*)(bb);
        bf16x8 b1 = *(const bf16x8*)(bb + 512);
        acc[0] = __builtin_amdgcn_mfma_f32_16x16x32_bf16(a, b0, acc[0], 0, 0, 0);
        acc[1] = __builtin_amdgcn_mfma_f32_16x16x32_bf16(a, b1, acc[1], 0, 0, 0);
    }
    int h = n0 >> 6;
    if (type < 2) {
        bf16* dst = (type == 0 ? qf : kf);
        int hf = (n0 & 32) >> 5;
        float sc = (type == 0 ? 0.125f : 1.0f);   // fold 1/sqrt(dk) into q
#pragma unroll
        for (int sub = 0; sub < 2; ++sub) {
#pragma unroll
            for (int r = 0; r < 4; ++r) {
                int i = i0 + w * 16 + lg * 4 + r;
                float v = (acc[sub][r] + bvec[n0 + sub * 16 + lr]) * sc;
                int lgp = sub * 2 + (lr >> 3);
                size_t off = (((size_t)(h * 128 + (i >> 4)) * 2 + hf) << 9) + lgp * 128 + (lg * 4 + r) * 8 + (lr & 7);
                dst[off] = (bf16)v;
            }
        }
    } else {
#pragma unroll
        for (int sub = 0; sub < 2; ++sub) {
#pragma unroll
            for (int r = 0; r < 4; ++r) {
                int node = i0 + w * 16 + lg * 4 + r;
                int dd = (n0 & 63) + sub * 16 + lr;
                float v = acc[sub][r] + bvec[n0 + sub * 16 + lr];
                size_t off = (((size_t)(h * 4 + (dd >> 4)) * 64 + (node >> 5)) << 9)
                           + ((node >> 3) & 3) * 128 + (dd & 15) * 8 + (node & 7);
                vf[off] = (bf16)v;
            }
        }
    }
}

// ---------------- generic bf16 MFMA GEMM, BN=64, 16 waves, 4-way K-split ----------------
#define FL_RES   1
#define FL_GELU  2
#define FL_OUTF  4

__device__ inline float gelu_f(float x) {
    float x3 = x * x * x;
    float u = 0.7978845608028654f * (x + 0.044715f * x3);
    return 0.5f * x * (1.f + tanhf(u));
}

__global__ __launch_bounds__(1024) void k_mm(const bf16* __restrict__ A, const bf16* __restrict__ Bt,
                                             const float* __restrict__ bvec, const float* __restrict__ res,
                                             float* __restrict__ outF, bf16* __restrict__ outB, int flags) {
    __shared__ bf16 Bs[32768];
    __shared__ float Osh[4][16][68];
    int t = threadIdx.x, w = t >> 6, l = t & 63, lr = l & 15, lg = l >> 4;
    int ti = w & 3, s = w >> 2;
    int j0 = blockIdx.x * 64, i0 = blockIdx.y * 64;
    const bf16* Bp = Bt + (size_t)j0 * HDIM;
#pragma unroll
    for (int rnd = 0; rnd < 4; ++rnd) {
        int tt = rnd * 1024 + t;
        int ks = tt >> 8, qq = (tt >> 6) & 3, mm = (tt >> 2) & 15, gg = tt & 3;
        bf16x8 v = *(const bf16x8*)(Bp + (size_t)(qq * 16 + mm) * HDIM + ks * 32 + gg * 8);
        *(bf16x8*)(Bs + tt * 8) = v;
    }
    __syncthreads();
    const bf16* ap = A + (size_t)(i0 + ti * 16 + lr) * HDIM + 8 * lg;
    f32x4 acc[4] = {};
#pragma unroll
    for (int kk = 0; kk < 4; ++kk) {
        int ks = s * 4 + kk;
        bf16x8 a = *(const bf16x8*)(ap + ks * 32);
        const bf16* bb = Bs + ks * 2048 + lr * 32 + lg * 8;
#pragma unroll
        for (int sub = 0; sub < 4; ++sub) {
            bf16x8 b = *(const bf16x8*)(bb + sub * 512);
            acc[sub] = __builtin_amdgcn_mfma_f32_16x16x32_bf16(a, b, acc[sub], 0, 0, 0);
        }
    }
    if (s == 0) {
#pragma unroll
        for (int sub = 0; sub < 4; ++sub)
#pragma unroll
            for (int r = 0; r < 4; ++r) Osh[ti][lg * 4 + r][sub * 16 + lr] = acc[sub][r];
    }
    __syncthreads();
    if (s == 1) {
#pragma unroll
        for (int sub = 0; sub < 4; ++sub)
#pragma unroll
            for (int r = 0; r < 4; ++r) Osh[ti][lg * 4 + r][sub * 16 + lr] += acc[sub][r];
    }
    __syncthreads();
    if (s == 2) {
#pragma unroll
        for (int sub = 0; sub < 4; ++sub)
#pragma unroll
            for (int r = 0; r < 4; ++r) Osh[ti][lg * 4 + r][sub * 16 + lr] += acc[sub][r];
    }
    __syncthreads();
    if (s == 3) {
#pragma unroll
        for (int sub = 0; sub < 4; ++sub) {
#pragma unroll
            for (int r = 0; r < 4; ++r) {
                int i = i0 + ti * 16 + lg * 4 + r;
                int j = j0 + sub * 16 + lr;
                float v = Osh[ti][lg * 4 + r][sub * 16 + lr] + acc[sub][r] + bvec[j];
                if (flags & FL_RES) v += res[(size_t)i * HDIM + j];
                if (flags & FL_GELU) v = gelu_f(v);
                if (flags & FL_OUTF) outF[(size_t)i * HDIM + j] = v;
                else outB[(size_t)i * HDIM + j] = (bf16)v;
            }
        }
    }
}

// ---------------- attention v3: swapped-QK MFMA flash, frag-direct loads ----------------
__global__ __launch_bounds__(1024) void k_attn2(const bf16* __restrict__ qf, const bf16* __restrict__ kf,
                                                const bf16* __restrict__ vf, const bf16* __restrict__ biasb,
                                                bf16* __restrict__ ob) {
    __shared__ char Pb[16 * 1024];           // per-wave 16i x 32j bf16 P^T tile, XOR-swizzled
    __shared__ float Osh[4][64][17];         // O^T merge buffer
    __shared__ float Msh[4][4][16], Lsh[4][4][16];
    int t = threadIdx.x, w = t >> 6, l = t & 63, lr = l & 15, lg = l >> 4;
    int ti = w & 3, s = w >> 2;
    int bid = blockIdx.x;
    int wid = (bid & 7) * 32 + (bid >> 3);   // XCD-chunk: 4 i-tiles x 8 heads per XCD
    int i0 = (wid >> 3) * 64, hh = wid & 7;
    int irow = i0 + ti * 16;

    const bf16* qb = qf + (((size_t)(hh * 128 + (irow >> 4)) * 2) << 9) + l * 8;
    bf16x8 qy0 = *(const bf16x8*)(qb);
    bf16x8 qy1 = *(const bf16x8*)(qb + 512);

    char* pwr = Pb + w * 1024 + lr * 64;
    unsigned kx = (unsigned)(lr & 6) << 3;

    float m_run = -3e38f, l_run = 0.f;
    f32x4 oacc[4] = {};

    for (int it = 0; it < 16; ++it) {
        int jb = s * 512 + it * 32;
        const bf16* kb = kf + (((size_t)(hh * 128 + (jb >> 4)) * 2) << 9) + l * 8;
        bf16x8 kx00 = *(const bf16x8*)(kb);
        bf16x8 kx01 = *(const bf16x8*)(kb + 512);
        bf16x8 kx10 = *(const bf16x8*)(kb + 1024);
        bf16x8 kx11 = *(const bf16x8*)(kb + 1536);
        const bf16* vb = vf + (((size_t)(hh * 4) * 64 + (jb >> 5)) << 9) + l * 8;
        bf16x8 vx0 = *(const bf16x8*)(vb);
        bf16x8 vx1 = *(const bf16x8*)(vb + 32768);
        bf16x8 vx2 = *(const bf16x8*)(vb + 65536);
        bf16x8 vx3 = *(const bf16x8*)(vb + 98304);
        const bf16* bp = biasb + (size_t)(irow + lr) * N_NODES + jb + lg * 4;
        bf16x4 bv0 = *(const bf16x4*)(bp);
        bf16x4 bv1 = *(const bf16x4*)(bp + 16);

        // swapped QK^T: S[j][i], rows j = lg*4+r (+16 jset), cols i = lr
        f32x4 s0v = {}, s1v = {};
        s0v = __builtin_amdgcn_mfma_f32_16x16x32_bf16(kx00, qy0, s0v, 0, 0, 0);
        s0v = __builtin_amdgcn_mfma_f32_16x16x32_bf16(kx01, qy1, s0v, 0, 0, 0);
        s1v = __builtin_amdgcn_mfma_f32_16x16x32_bf16(kx10, qy0, s1v, 0, 0, 0);
        s1v = __builtin_amdgcn_mfma_f32_16x16x32_bf16(kx11, qy1, s1v, 0, 0, 0);

        float p0[4], p1[4];
        float mt = -3e38f;
#pragma unroll
        for (int r = 0; r < 4; ++r) {
            p0[r] = s0v[r] + (float)bv0[r];
            p1[r] = s1v[r] + (float)bv1[r];
            mt = fmaxf(mt, fmaxf(p0[r], p1[r]));
        }
        mt = fmaxf(mt, __shfl_xor(mt, 16));
        mt = fmaxf(mt, __shfl_xor(mt, 32));
        float mn = fmaxf(m_run, mt);
        float alpha = __expf(m_run - mn);
        m_run = mn;
        float ps = 0.f;
        bf16x4 pk0, pk1;
#pragma unroll
        for (int r = 0; r < 4; ++r) {
            p0[r] = __expf(p0[r] - mn);
            p1[r] = __expf(p1[r] - mn);
            ps += p0[r] + p1[r];
            pk0[r] = (bf16)p0[r];
            pk1[r] = (bf16)p1[r];
        }
        ps += __shfl_xor(ps, 16);
        ps += __shfl_xor(ps, 32);
        l_run = l_run * alpha + ps;

        *(bf16x4*)(pwr + ((lg * 8) ^ kx)) = pk0;
        *(bf16x4*)(pwr + ((32 + lg * 8) ^ kx)) = pk1;
#pragma unroll
        for (int d = 0; d < 4; ++d) oacc[d] *= alpha;
        asm volatile("s_waitcnt lgkmcnt(0)" ::: "memory");
        __builtin_amdgcn_sched_barrier(0x20);   // only VMEM reads may cross
        bf16x8 py = *(bf16x8*)(Pb + w * 1024 + lr * 64 + ((lg * 16) ^ kx));
        oacc[0] = __builtin_amdgcn_mfma_f32_16x16x32_bf16(vx0, py, oacc[0], 0, 0, 0);
        oacc[1] = __builtin_amdgcn_mfma_f32_16x16x32_bf16(vx1, py, oacc[1], 0, 0, 0);
        oacc[2] = __builtin_amdgcn_mfma_f32_16x16x32_bf16(vx2, py, oacc[2], 0, 0, 0);
        oacc[3] = __builtin_amdgcn_mfma_f32_16x16x32_bf16(vx3, py, oacc[3], 0, 0, 0);
    }

    // ---- merge 4 j-splits ----
    __syncthreads();
    if (lg == 0) { Msh[ti][s][lr] = m_run; Lsh[ti][s][lr] = l_run; }
    __syncthreads();
    float m0 = Msh[ti][0][lr], m1 = Msh[ti][1][lr], m2 = Msh[ti][2][lr], m3 = Msh[ti][3][lr];
    float mtot = fmaxf(fmaxf(m0, m1), fmaxf(m2, m3));
    float l_tot = Lsh[ti][0][lr] * __expf(m0 - mtot) + Lsh[ti][1][lr] * __expf(m1 - mtot)
                + Lsh[ti][2][lr] * __expf(m2 - mtot) + Lsh[ti][3][lr] * __expf(m3 - mtot);
    float fac = __expf(m_run - mtot);
#pragma unroll
    for (int d = 0; d < 4; ++d) oacc[d] *= fac;
    if (s == 0) {
#pragma unroll
        for (int db = 0; db < 4; ++db)
#pragma unroll
            for (int r = 0; r < 4; ++r) Osh[ti][db * 16 + lg * 4 + r][lr] = oacc[db][r];
    }
    __syncthreads();
    if (s == 1) {
#pragma unroll
        for (int db = 0; db < 4; ++db)
#pragma unroll
            for (int r = 0; r < 4; ++r) Osh[ti][db * 16 + lg * 4 + r][lr] += oacc[db][r];
    }
    __syncthreads();
    if (s == 2) {
#pragma unroll
        for (int db = 0; db < 4; ++db)
#pragma unroll
            for (int r = 0; r < 4; ++r) Osh[ti][db * 16 + lg * 4 + r][lr] += oacc[db][r];
    }
    __syncthreads();
    if (s == 3) {
        float inv = 1.f / l_tot;
#pragma unroll
        for (int db = 0; db < 4; ++db) {
            bf16x4 o4;
#pragma unroll
            for (int r = 0; r < 4; ++r)
                o4[r] = (bf16)((Osh[ti][db * 16 + lg * 4 + r][lr] + oacc[db][r]) * inv);
            *(bf16x4*)(ob + (size_t)(irow + lr) * HDIM + hh * DK + db * 16 + lg * 4) = o4;
        }
    }
}

// ---------------- f32 GEMM (final 512->64 projection only) ----------------
__global__ __launch_bounds__(256) void k_gemm(const float* __restrict__ A, const float* __restrict__ B,
                                              const float* __restrict__ bvec, float* __restrict__ C,
                                              int M, int Nc, int K) {
    __shared__ float As[16][68];
    __shared__ float Bs[16][68];
    int t = threadIdx.x;
    int tm = t >> 4, tn = t & 15;
    int i0 = blockIdx.y * 64, j0 = blockIdx.x * 64;
    int ar = t >> 2, aq = t & 3;
    int br = t >> 4, bq = t & 15;
    float acc[4][4] = {};
    for (int k0 = 0; k0 < K; k0 += 16) {
        float4 av = *(const float4*)(A + (size_t)(i0 + ar) * K + k0 + aq * 4);
        As[aq * 4 + 0][ar] = av.x;
        As[aq * 4 + 1][ar] = av.y;
        As[aq * 4 + 2][ar] = av.z;
        As[aq * 4 + 3][ar] = av.w;
        *(float4*)&Bs[br][bq * 4] = *(const float4*)(B + (size_t)(k0 + br) * Nc + j0 + bq * 4);
        __syncthreads();
#pragma unroll
        for (int k = 0; k < 16; ++k) {
            float4 a4 = *(const float4*)&As[k][tm * 4];
            float4 b4 = *(const float4*)&Bs[k][tn * 4];
            float avv[4] = {a4.x, a4.y, a4.z, a4.w};
            float bvv[4] = {b4.x, b4.y, b4.z, b4.w};
#pragma unroll
            for (int r = 0; r < 4; ++r)
#pragma unroll
                for (int c = 0; c < 4; ++c) acc[r][c] += avv[r] * bvv[c];
        }
        __syncthreads();
    }
#pragma unroll
    for (int r = 0; r < 4; ++r) {
#pragma unroll
        for (int c = 0; c < 4; ++c) {
            int i = i0 + tm * 4 + r;
            int j = j0 + tn * 4 + c;
            C[(size_t)i * Nc + j] = acc[r][c] + bvec[j];
        }
    }
}

extern "C" void kernel_launch(void* const* d_in, const int* in_sizes, int n_in,
                              void* d_out, int out_size, void* d_ws, size_t ws_size,
                              hipStream_t stream) {
    const float* x      = (const float*)d_in[0];
    const int*   ei     = (const int*)d_in[1];
    const float* eattr  = (const float*)d_in[2];
    const int*   epaths = (const int*)d_in[4];
    const float* Wn     = (const float*)d_in[5];
    const float* bn     = (const float*)d_in[6];
    const float* We     = (const float*)d_in[7];
    const float* be     = (const float*)d_in[8];
    const float* zin    = (const float*)d_in[9];
    const float* zout   = (const float*)d_in[10];
    const float* bsp    = (const float*)d_in[11];
    const float* ev     = (const float*)d_in[12];
    const float* ln1s   = (const float*)d_in[13];
    const float* ln1b   = (const float*)d_in[14];
    const float* Wq     = (const float*)d_in[15];
    const float* bq     = (const float*)d_in[16];
    const float* Wk     = (const float*)d_in[17];
    const float* bk     = (const float*)d_in[18];
    const float* Wv     = (const float*)d_in[19];
    const float* bv     = (const float*)d_in[20];
    const float* Wo     = (const float*)d_in[21];
    const float* bo     = (const float*)d_in[22];
    const float* ln2s   = (const float*)d_in[23];
    const float* ln2b   = (const float*)d_in[24];
    const float* W1     = (const float*)d_in[25];
    const float* b1     = (const float*)d_in[26];
    const float* W2     = (const float*)d_in[27];
    const float* b2     = (const float*)d_in[28];
    const float* Wout   = (const float*)d_in[29];
    const float* bout   = (const float*)d_in[30];

    char* base = (char*)d_ws;
    size_t off = 0;
    auto alloc = [&](size_t bytes) { char* p = base + off; off = (off + bytes + 255) & ~(size_t)255; return p; };
    bf16*  bias   = (bf16*)alloc((size_t)N_NODES * N_NODES * 2);
    float* h      = (float*)alloc((size_t)N_NODES * HDIM * 4);
    bf16*  wbuf   = (bf16*)alloc((size_t)NEDGE * LPATH * 2);
    float* Mb     = (float*)alloc(96 * 4);
    float* c5     = (float*)alloc(16 * 4);
    int*   deg    = (int*)alloc(2 * N_NODES * 4);
    bf16*  y_bf   = (bf16*)alloc((size_t)N_NODES * HDIM * 2);
    bf16*  qfb    = (bf16*)alloc((size_t)NHEAD * 128 * 2 * 512 * 2);
    bf16*  kfb    = (bf16*)alloc((size_t)NHEAD * 128 * 2 * 512 * 2);
    bf16*  vfb    = (bf16*)alloc((size_t)NHEAD * 4 * 64 * 512 * 2);
    bf16*  ob_bf  = (bf16*)alloc((size_t)N_NODES * HDIM * 2);
    bf16*  t1_bf  = (bf16*)alloc((size_t)N_NODES * HDIM * 2);
    bf16*  Wt     = (bf16*)alloc((size_t)NLAYER * 6 * HDIM * HDIM * 2);
    int* din = deg;
    int* dout = deg + N_NODES;

    hipMemsetAsync(deg, 0, 2 * N_NODES * sizeof(int), stream);

    k_edge_mat<<<1, 128, 0, stream>>>(We, be, ev, Mb, c5);
    k_edge_w<<<NEDGE / 256, 256, 0, stream>>>(eattr, Mb, c5, wbuf);
    k_deg<<<NEDGE / 256, 256, 0, stream>>>(ei, din, dout);
    k_node_proj<<<N_NODES, 256, 0, stream>>>(x, Wn, bn, zin, zout, din, dout, h);
    k_bias<<<(N_NODES * (size_t)N_NODES) / 1024, 256, 0, stream>>>(epaths, wbuf, bsp, bias);
    k_wprep<<<dim3(64, 24), 256, 0, stream>>>(Wq, Wk, Wv, Wo, W1, W2, Wt);

    dim3 gqkv(48, 32);
    dim3 gmm(8, 32);

    for (int l = 0; l < NLAYER; ++l) {
        const bf16* Wt_l = Wt + (size_t)l * 6 * HDIM * HDIM;
        size_t bOff = (size_t)l * HDIM;
        k_ln<<<N_NODES, 256, 0, stream>>>(h, ln1s + bOff, ln1b + bOff, y_bf);
        k_qkv<<<gqkv, 256, 0, stream>>>(y_bf, Wt_l, bq + bOff, bk + bOff, bv + bOff, qfb, kfb, vfb);
        k_attn2<<<256, 1024, 0, stream>>>(qfb, kfb, vfb, bias, ob_bf);
        k_mm<<<gmm, 1024, 0, stream>>>(ob_bf, Wt_l + (size_t)3 * HDIM * HDIM, bo + bOff, h, h, nullptr, FL_RES | FL_OUTF);
        k_ln<<<N_NODES, 256, 0, stream>>>(h, ln2s + bOff, ln2b + bOff, y_bf);
        k_mm<<<gmm, 1024, 0, stream>>>(y_bf, Wt_l + (size_t)4 * HDIM * HDIM, b1 + bOff, nullptr, nullptr, t1_bf, FL_GELU);
        k_mm<<<gmm, 1024, 0, stream>>>(t1_bf, Wt_l + (size_t)5 * HDIM * HDIM, b2 + bOff, h, h, nullptr, FL_RES | FL_OUTF);
    }
    k_gemm<<<dim3(1, 32), 256, 0, stream>>>(h, Wout, bout, (float*)d_out, N_NODES, ODIM, HDIM);
}

// Round 6
// 501.707 us; speedup vs baseline: 1.2892x; 1.0082x over previous
//
#include <hip/hip_runtime.h>
#include <hip/hip_bf16.h>
#include <math.h>

#define N_NODES 2048
#define NEDGE   65536
#define FDIM    128
#define HDIM    512
#define EFD     16
#define EDD     64
#define LPATH   5
#define NLAYER  4
#define NHEAD   8
#define DK      64
#define ODIM    64
#define MAXDEG  64
#define PHALF   2097152   // pairs per half-pass (N*N/2)

typedef __bf16 bf16;
typedef bf16 bf16x8 __attribute__((ext_vector_type(8)));
typedef bf16 bf16x4 __attribute__((ext_vector_type(4)));
typedef float f32x4 __attribute__((ext_vector_type(4)));
typedef unsigned short u16;
typedef u16 u16x4 __attribute__((ext_vector_type(4)));

// ---------------- small precompute kernels ----------------

__global__ void k_edge_mat(const float* __restrict__ W_edge, const float* __restrict__ b_edge,
                           const float* __restrict__ ev, float* __restrict__ M, float* __restrict__ c5) {
    int t = threadIdx.x;
    if (t < EFD * LPATH) {
        int i = t / LPATH, j = t % LPATH;
        float acc = 0.f;
        for (int k = 0; k < EDD; ++k) acc += W_edge[i * EDD + k] * ev[j * EDD + k];
        M[t] = acc;
    } else if (t >= 80 && t < 80 + LPATH) {
        int j = t - 80;
        float acc = 0.f;
        for (int k = 0; k < EDD; ++k) acc += b_edge[k] * ev[j * EDD + k];
        c5[j] = acc;
    }
}

// writes w as 5 planes: wT[l][e]
__global__ __launch_bounds__(256) void k_edge_w(const float* __restrict__ ea, const float* __restrict__ M,
                                                const float* __restrict__ c5, bf16* __restrict__ wT) {
    __shared__ float sM[80];
    __shared__ float sc[8];
    int t = threadIdx.x;
    if (t < 80) sM[t] = M[t];
    if (t < LPATH) sc[t] = c5[t];
    __syncthreads();
    int e = blockIdx.x * 256 + t;
    const float4* p = (const float4*)(ea + (size_t)e * EFD);
    float4 a0 = p[0], a1 = p[1], a2 = p[2], a3 = p[3];
    float a[16] = {a0.x, a0.y, a0.z, a0.w, a1.x, a1.y, a1.z, a1.w,
                   a2.x, a2.y, a2.z, a2.w, a3.x, a3.y, a3.z, a3.w};
    float out[LPATH];
#pragma unroll
    for (int j = 0; j < LPATH; ++j) out[j] = sc[j];
#pragma unroll
    for (int i = 0; i < 16; ++i)
#pragma unroll
        for (int j = 0; j < LPATH; ++j) out[j] += a[i] * sM[i * LPATH + j];
#pragma unroll
    for (int j = 0; j < LPATH; ++j) wT[(size_t)j * NEDGE + e] = (bf16)out[j];
}

__global__ __launch_bounds__(256) void k_deg(const int* __restrict__ ei, int* __restrict__ din, int* __restrict__ dout) {
    int e = blockIdx.x * 256 + threadIdx.x;
    if (e < NEDGE) {
        atomicAdd(&dout[ei[e]], 1);
        atomicAdd(&din[ei[NEDGE + e]], 1);
    }
}

// ---------------- bias pipeline: pack (u16 idx planes + validity mask) then LDS-sliced gather ----------------
__global__ __launch_bounds__(256) void k_pack(const int* __restrict__ ep, u16* __restrict__ idxp,
                                              unsigned char* __restrict__ maskp) {
    int tid4 = blockIdx.x * 256 + threadIdx.x;   // 4 pairs per thread
    const int4* p = (const int4*)(ep + (size_t)tid4 * 20);
    int4 q0 = p[0], q1 = p[1], q2 = p[2], q3 = p[3], q4 = p[4];
    int e[20] = {q0.x, q0.y, q0.z, q0.w, q1.x, q1.y, q1.z, q1.w,
                 q2.x, q2.y, q2.z, q2.w, q3.x, q3.y, q3.z, q3.w,
                 q4.x, q4.y, q4.z, q4.w};
    u16x4 out[LPATH];
    unsigned m[4] = {0, 0, 0, 0};
#pragma unroll
    for (int pp = 0; pp < 4; ++pp) {
#pragma unroll
        for (int l = 0; l < LPATH; ++l) {
            int v = e[pp * 5 + l];
            if (v >= 0) m[pp] |= (1u << l);
            out[l][pp] = (u16)v;   // -1 -> 0xFFFF (in-bounds dummy, masked out)
        }
    }
#pragma unroll
    for (int l = 0; l < LPATH; ++l)
        *(u16x4*)(idxp + (size_t)l * PHALF + tid4 * 4) = out[l];
    unsigned packed = m[0] | (m[1] << 8) | (m[2] << 16) | (m[3] << 24);
    *(unsigned*)(maskp + (size_t)tid4 * 4) = packed;
}

__global__ __launch_bounds__(1024) void k_bias2(const u16* __restrict__ idxp, const unsigned char* __restrict__ maskp,
                                                const bf16* __restrict__ wT, const float* __restrict__ bsp,
                                                bf16* __restrict__ bias) {
    __shared__ bf16 wsl[NEDGE];   // 128 KB slice
    int t = threadIdx.x;
    int base = blockIdx.x * 8192;
    unsigned char msk[8];
    float csum[8] = {};
#pragma unroll
    for (int r = 0; r < 8; ++r) msk[r] = maskp[base + r * 1024 + t];
    for (int l = 0; l < LPATH; ++l) {
        __syncthreads();   // previous gathers done before overwrite
#pragma unroll
        for (int u = 0; u < 4; ++u) {
            int o = u * 16384 + t * 16;
            *(bf16x8*)&wsl[o]     = *(const bf16x8*)&wT[(size_t)l * NEDGE + o];
            *(bf16x8*)&wsl[o + 8] = *(const bf16x8*)&wT[(size_t)l * NEDGE + o + 8];
        }
        u16 ei[8];
#pragma unroll
        for (int r = 0; r < 8; ++r) ei[r] = idxp[(size_t)l * PHALF + base + r * 1024 + t];
        __syncthreads();
#pragma unroll
        for (int r = 0; r < 8; ++r) {
            float v = (float)wsl[ei[r]];
            csum[r] += ((msk[r] >> l) & 1) ? v : 0.f;
        }
    }
#pragma unroll
    for (int r = 0; r < 8; ++r) {
        int cnt = __popc((int)msk[r]);
        float b = cnt ? bsp[cnt - 1] + csum[r] / (float)cnt : 0.f;
        bias[base + r * 1024 + t] = (bf16)b;
    }
}

// ---------------- layernorm: f32 in, bf16 out ----------------
__global__ __launch_bounds__(256) void k_ln(const float* __restrict__ h, const float* __restrict__ sc,
                                            const float* __restrict__ bi, bf16* __restrict__ y) {
    int i = blockIdx.x, t = threadIdx.x;
    float v0 = h[(size_t)i * HDIM + t];
    float v1 = h[(size_t)i * HDIM + 256 + t];
    float s = v0 + v1, q = v0 * v0 + v1 * v1;
#pragma unroll
    for (int m = 1; m < 64; m <<= 1) { s += __shfl_xor(s, m); q += __shfl_xor(q, m); }
    __shared__ float ssum[4], sq[4];
    int wv = t >> 6;
    if ((t & 63) == 0) { ssum[wv] = s; sq[wv] = q; }
    __syncthreads();
    float S = ssum[0] + ssum[1] + ssum[2] + ssum[3];
    float Q = sq[0] + sq[1] + sq[2] + sq[3];
    float mean = S * (1.f / HDIM);
    float var = Q * (1.f / HDIM) - mean * mean;
    float r = rsqrtf(var + 1e-5f);
    y[(size_t)i * HDIM + t] = (bf16)((v0 - mean) * r * sc[t] + bi[t]);
    y[(size_t)i * HDIM + 256 + t] = (bf16)((v1 - mean) * r * sc[256 + t] + bi[256 + t]);
}

// ---------------- weight prep: f32 [K][N] -> bf16 W^T [N][K] ----------------
__global__ __launch_bounds__(256) void k_wprep(const float* __restrict__ Wq, const float* __restrict__ Wk,
                                               const float* __restrict__ Wv, const float* __restrict__ Wo,
                                               const float* __restrict__ W1, const float* __restrict__ W2,
                                               bf16* __restrict__ Wt) {
    __shared__ float Ls[64][68];
    int m = blockIdx.y;
    int lay = m / 6, type = m % 6;
    const float* src = type == 0 ? Wq : type == 1 ? Wk : type == 2 ? Wv : type == 3 ? Wo : type == 4 ? W1 : W2;
    src += (size_t)lay * (HDIM * HDIM);
    int q = blockIdx.x;
    int tk = q >> 3, tn = q & 7;
    int t = threadIdx.x;
    int rr = t >> 4, cc = t & 15;
#pragma unroll
    for (int u = 0; u < 4; ++u) {
        float4 v = *(const float4*)(src + (size_t)(tk * 64 + rr + 16 * u) * HDIM + tn * 64 + cc * 4);
        *(float4*)&Ls[rr + 16 * u][cc * 4] = v;
    }
    __syncthreads();
    int nl = t >> 2, kc = t & 3;
    bf16 tmp[16];
#pragma unroll
    for (int u = 0; u < 16; ++u) tmp[u] = (bf16)Ls[kc * 16 + u][nl];
    bf16* dst = Wt + (size_t)m * (HDIM * HDIM) + (size_t)(tn * 64 + nl) * HDIM + tk * 64 + kc * 16;
    *(bf16x8*)(dst) = *(bf16x8*)&tmp[0];
    *(bf16x8*)(dst + 8) = *(bf16x8*)&tmp[8];
}

// Wn: f32 [128][512] -> bf16 WnT [512][128]
__global__ __launch_bounds__(256) void k_wprepn(const float* __restrict__ Wn, bf16* __restrict__ WnT) {
    __shared__ float Ls[64][68];
    int b = blockIdx.x;
    int tk = b >> 3, tn = b & 7;
    int t = threadIdx.x, rr = t >> 4, cc = t & 15;
#pragma unroll
    for (int u = 0; u < 4; ++u) {
        float4 v = *(const float4*)(Wn + (size_t)(tk * 64 + rr + 16 * u) * HDIM + tn * 64 + cc * 4);
        *(float4*)&Ls[rr + 16 * u][cc * 4] = v;
    }
    __syncthreads();
    int nl = t >> 2, kc = t & 3;
    bf16 tmp[16];
#pragma unroll
    for (int u = 0; u < 16; ++u) tmp[u] = (bf16)Ls[kc * 16 + u][nl];
    bf16* dst = WnT + (size_t)(tn * 64 + nl) * FDIM + tk * 64 + kc * 16;
    *(bf16x8*)dst = *(bf16x8*)&tmp[0];
    *(bf16x8*)(dst + 8) = *(bf16x8*)&tmp[8];
}

__global__ __launch_bounds__(256) void k_xcast(const float* __restrict__ x, bf16* __restrict__ xb) {
    int i = blockIdx.x * 256 + threadIdx.x;
    float4 v = *(const float4*)(x + (size_t)i * 4);
    bf16x4 o;
    o[0] = (bf16)v.x; o[1] = (bf16)v.y; o[2] = (bf16)v.z; o[3] = (bf16)v.w;
    *(bf16x4*)(xb + (size_t)i * 4) = o;
}

// node projection as MFMA GEMM (K=128) + degree-embedding epilogue
__global__ __launch_bounds__(256) void k_nmm(const bf16* __restrict__ A, const bf16* __restrict__ Bt,
                                             const float* __restrict__ bn, const float* __restrict__ zin,
                                             const float* __restrict__ zout, const int* __restrict__ din,
                                             const int* __restrict__ dout, float* __restrict__ h) {
    __shared__ bf16 Bs[8192];   // 64 n-rows x 128 K, frag-contiguous
    int t = threadIdx.x, w = t >> 6, l = t & 63, lr = l & 15, lg = l >> 4;
    int j0 = blockIdx.x * 64, i0 = blockIdx.y * 64;
    const bf16* Bp = Bt + (size_t)j0 * FDIM;
#pragma unroll
    for (int rnd = 0; rnd < 4; ++rnd) {
        int tt = rnd * 256 + t;
        int ks = tt >> 8, qq = (tt >> 6) & 3, mm = (tt >> 2) & 15, gg = tt & 3;
        *(bf16x8*)(Bs + tt * 8) = *(const bf16x8*)(Bp + (size_t)(qq * 16 + mm) * FDIM + ks * 32 + gg * 8);
    }
    __syncthreads();
    const bf16* ap = A + (size_t)(i0 + w * 16 + lr) * FDIM + 8 * lg;
    f32x4 acc[4] = {};
#pragma unroll
    for (int ks = 0; ks < 4; ++ks) {
        bf16x8 a = *(const bf16x8*)(ap + ks * 32);
        const bf16* bb = Bs + ks * 2048 + lr * 32 + lg * 8;
#pragma unroll
        for (int sub = 0; sub < 4; ++sub)
            acc[sub] = __builtin_amdgcn_mfma_f32_16x16x32_bf16(a, *(const bf16x8*)(bb + sub * 512), acc[sub], 0, 0, 0);
    }
#pragma unroll
    for (int r = 0; r < 4; ++r) {
        int i = i0 + w * 16 + lg * 4 + r;
        int di = min(din[i], MAXDEG - 1), dz = min(dout[i], MAXDEG - 1);
#pragma unroll
        for (int sub = 0; sub < 4; ++sub) {
            int j = j0 + sub * 16 + lr;
            h[(size_t)i * HDIM + j] = acc[sub][r] + bn[j] + zin[(size_t)di * HDIM + j] + zout[(size_t)dz * HDIM + j];
        }
    }
}

// ---------------- fused QKV GEMM -> frag-contiguous q/k/v layouts ----------------
__global__ __launch_bounds__(256) void k_qkv(const bf16* __restrict__ A, const bf16* __restrict__ Wt_l,
                                             const float* __restrict__ bq, const float* __restrict__ bk,
                                             const float* __restrict__ bv, bf16* __restrict__ qf,
                                             bf16* __restrict__ kf, bf16* __restrict__ vf) {
    __shared__ bf16 Bs[16384];
    int t = threadIdx.x, w = t >> 6, l = t & 63, lr = l & 15, lg = l >> 4;
    int j0 = blockIdx.x * 32, i0 = blockIdx.y * 64;
    int type = j0 >> 9, n0 = j0 & 511;
    const bf16* Bp = Wt_l + (size_t)type * (HDIM * HDIM) + (size_t)n0 * HDIM;
#pragma unroll
    for (int rnd = 0; rnd < 8; ++rnd) {
        int tt = rnd * 256 + t;
        int ks = tt >> 7, qq = (tt >> 6) & 1, mm = (tt >> 2) & 15, gg = tt & 3;
        bf16x8 v = *(const bf16x8*)(Bp + (size_t)(qq * 16 + mm) * HDIM + ks * 32 + gg * 8);
        *(bf16x8*)(Bs + tt * 8) = v;
    }
    __syncthreads();
    const bf16* ap = A + (size_t)(i0 + w * 16 + lr) * HDIM + 8 * lg;
    const float* bvec = (type == 0 ? bq : type == 1 ? bk : bv);
    f32x4 acc[2] = {};
#pragma unroll 4
    for (int ks = 0; ks < 16; ++ks) {
        bf16x8 a  = *(const bf16x8*)(ap + ks * 32);
        const bf16* bb = Bs + ks * 1024 + lr * 32 + lg * 8;
        bf16x8 b0 = *(const bf16x8*)(bb);
        bf16x8 b1 = *(const bf16x8*)(bb + 512);
        acc[0] = __builtin_amdgcn_mfma_f32_16x16x32_bf16(a, b0, acc[0], 0, 0, 0);
        acc[1] = __builtin_amdgcn_mfma_f32_16x16x32_bf16(a, b1, acc[1], 0, 0, 0);
    }
    int h = n0 >> 6;
    if (type < 2) {
        bf16* dst = (type == 0 ? qf : kf);
        int hf = (n0 & 32) >> 5;
        float sc = (type == 0 ? 0.125f : 1.0f);
#pragma unroll
        for (int sub = 0; sub < 2; ++sub) {
#pragma unroll
            for (int r = 0; r < 4; ++r) {
                int i = i0 + w * 16 + lg * 4 + r;
                float v = (acc[sub][r] + bvec[n0 + sub * 16 + lr]) * sc;
                int lgp = sub * 2 + (lr >> 3);
                size_t off = (((size_t)(h * 128 + (i >> 4)) * 2 + hf) << 9) + lgp * 128 + (lg * 4 + r) * 8 + (lr & 7);
                dst[off] = (bf16)v;
            }
        }
    } else {
#pragma unroll
        for (int sub = 0; sub < 2; ++sub) {
#pragma unroll
            for (int r = 0; r < 4; ++r) {
                int node = i0 + w * 16 + lg * 4 + r;
                int dd = (n0 & 63) + sub * 16 + lr;
                float v = acc[sub][r] + bvec[n0 + sub * 16 + lr];
                size_t off = (((size_t)(h * 4 + (dd >> 4)) * 64 + (node >> 5)) << 9)
                           + ((node >> 3) & 3) * 128 + (dd & 15) * 8 + (node & 7);
                vf[off] = (bf16)v;
            }
        }
    }
}

// ---------------- generic bf16 MFMA GEMM, BN=64, 16 waves, 4-way K-split ----------------
#define FL_RES   1
#define FL_GELU  2
#define FL_OUTF  4

__device__ inline float gelu_f(float x) {
    float x3 = x * x * x;
    float u = 0.7978845608028654f * (x + 0.044715f * x3);
    return 0.5f * x * (1.f + tanhf(u));
}

__global__ __launch_bounds__(1024) void k_mm(const bf16* __restrict__ A, const bf16* __restrict__ Bt,
                                             const float* __restrict__ bvec, const float* __restrict__ res,
                                             float* __restrict__ outF, bf16* __restrict__ outB, int flags) {
    __shared__ bf16 Bs[32768];
    __shared__ float Osh[4][16][68];
    int t = threadIdx.x, w = t >> 6, l = t & 63, lr = l & 15, lg = l >> 4;
    int ti = w & 3, s = w >> 2;
    int j0 = blockIdx.x * 64, i0 = blockIdx.y * 64;
    const bf16* Bp = Bt + (size_t)j0 * HDIM;
#pragma unroll
    for (int rnd = 0; rnd < 4; ++rnd) {
        int tt = rnd * 1024 + t;
        int ks = tt >> 8, qq = (tt >> 6) & 3, mm = (tt >> 2) & 15, gg = tt & 3;
        bf16x8 v = *(const bf16x8*)(Bp + (size_t)(qq * 16 + mm) * HDIM + ks * 32 + gg * 8);
        *(bf16x8*)(Bs + tt * 8) = v;
    }
    __syncthreads();
    const bf16* ap = A + (size_t)(i0 + ti * 16 + lr) * HDIM + 8 * lg;
    f32x4 acc[4] = {};
#pragma unroll
    for (int kk = 0; kk < 4; ++kk) {
        int ks = s * 4 + kk;
        bf16x8 a = *(const bf16x8*)(ap + ks * 32);
        const bf16* bb = Bs + ks * 2048 + lr * 32 + lg * 8;
#pragma unroll
        for (int sub = 0; sub < 4; ++sub) {
            bf16x8 b = *(const bf16x8*)(bb + sub * 512);
            acc[sub] = __builtin_amdgcn_mfma_f32_16x16x32_bf16(a, b, acc[sub], 0, 0, 0);
        }
    }
    if (s == 0) {
#pragma unroll
        for (int sub = 0; sub < 4; ++sub)
#pragma unroll
            for (int r = 0; r < 4; ++r) Osh[ti][lg * 4 + r][sub * 16 + lr] = acc[sub][r];
    }
    __syncthreads();
    if (s == 1) {
#pragma unroll
        for (int sub = 0; sub < 4; ++sub)
#pragma unroll
            for (int r = 0; r < 4; ++r) Osh[ti][lg * 4 + r][sub * 16 + lr] += acc[sub][r];
    }
    __syncthreads();
    if (s == 2) {
#pragma unroll
        for (int sub = 0; sub < 4; ++sub)
#pragma unroll
            for (int r = 0; r < 4; ++r) Osh[ti][lg * 4 + r][sub * 16 + lr] += acc[sub][r];
    }
    __syncthreads();
    if (s == 3) {
#pragma unroll
        for (int sub = 0; sub < 4; ++sub) {
#pragma unroll
            for (int r = 0; r < 4; ++r) {
                int i = i0 + ti * 16 + lg * 4 + r;
                int j = j0 + sub * 16 + lr;
                float v = Osh[ti][lg * 4 + r][sub * 16 + lr] + acc[sub][r] + bvec[j];
                if (flags & FL_RES) v += res[(size_t)i * HDIM + j];
                if (flags & FL_GELU) v = gelu_f(v);
                if (flags & FL_OUTF) outF[(size_t)i * HDIM + j] = v;
                else outB[(size_t)i * HDIM + j] = (bf16)v;
            }
        }
    }
}

// ---------------- attention: swapped-QK MFMA flash, frag-direct loads, defer-max, setprio ----------------
__global__ __launch_bounds__(1024) void k_attn2(const bf16* __restrict__ qf, const bf16* __restrict__ kf,
                                                const bf16* __restrict__ vf, const bf16* __restrict__ biasb,
                                                bf16* __restrict__ ob) {
    __shared__ char Pb[16 * 1024];
    __shared__ float Osh[4][64][17];
    __shared__ float Msh[4][4][16], Lsh[4][4][16];
    int t = threadIdx.x, w = t >> 6, l = t & 63, lr = l & 15, lg = l >> 4;
    int ti = w & 3, s = w >> 2;
    int bid = blockIdx.x;
    int wid = (bid & 7) * 32 + (bid >> 3);
    int i0 = (wid >> 3) * 64, hh = wid & 7;
    int irow = i0 + ti * 16;

    const bf16* qb = qf + (((size_t)(hh * 128 + (irow >> 4)) * 2) << 9) + l * 8;
    bf16x8 qy0 = *(const bf16x8*)(qb);
    bf16x8 qy1 = *(const bf16x8*)(qb + 512);

    char* pwr = Pb + w * 1024 + lr * 64;
    unsigned kx = (unsigned)(lr & 6) << 3;

    float m_run = -3e38f, l_run = 0.f;
    f32x4 oacc[4] = {};

    for (int it = 0; it < 16; ++it) {
        int jb = s * 512 + it * 32;
        const bf16* kb = kf + (((size_t)(hh * 128 + (jb >> 4)) * 2) << 9) + l * 8;
        bf16x8 kx00 = *(const bf16x8*)(kb);
        bf16x8 kx01 = *(const bf16x8*)(kb + 512);
        bf16x8 kx10 = *(const bf16x8*)(kb + 1024);
        bf16x8 kx11 = *(const bf16x8*)(kb + 1536);
        const bf16* vb = vf + (((size_t)(hh * 4) * 64 + (jb >> 5)) << 9) + l * 8;
        bf16x8 vx0 = *(const bf16x8*)(vb);
        bf16x8 vx1 = *(const bf16x8*)(vb + 32768);
        bf16x8 vx2 = *(const bf16x8*)(vb + 65536);
        bf16x8 vx3 = *(const bf16x8*)(vb + 98304);
        const bf16* bp = biasb + (size_t)(irow + lr) * N_NODES + jb + lg * 4;
        bf16x4 bv0 = *(const bf16x4*)(bp);
        bf16x4 bv1 = *(const bf16x4*)(bp + 16);

        f32x4 s0v = {}, s1v = {};
        __builtin_amdgcn_s_setprio(1);
        s0v = __builtin_amdgcn_mfma_f32_16x16x32_bf16(kx00, qy0, s0v, 0, 0, 0);
        s0v = __builtin_amdgcn_mfma_f32_16x16x32_bf16(kx01, qy1, s0v, 0, 0, 0);
        s1v = __builtin_amdgcn_mfma_f32_16x16x32_bf16(kx10, qy0, s1v, 0, 0, 0);
        s1v = __builtin_amdgcn_mfma_f32_16x16x32_bf16(kx11, qy1, s1v, 0, 0, 0);
        __builtin_amdgcn_s_setprio(0);

        float p0[4], p1[4];
        float mt = -3e38f;
#pragma unroll
        for (int r = 0; r < 4; ++r) {
            p0[r] = s0v[r] + (float)bv0[r];
            p1[r] = s1v[r] + (float)bv1[r];
            mt = fmaxf(mt, fmaxf(p0[r], p1[r]));
        }
        mt = fmaxf(mt, __shfl_xor(mt, 16));
        mt = fmaxf(mt, __shfl_xor(mt, 32));
        // defer-max (T13): skip rescale when per-tile max growth <= 8
        if (!__all(mt <= m_run + 8.f)) {
            float mn = fmaxf(m_run, mt);
            float alpha = __expf(m_run - mn);
            l_run *= alpha;
#pragma unroll
            for (int d = 0; d < 4; ++d) oacc[d] *= alpha;
            m_run = mn;
        }
        float ps = 0.f;
        bf16x4 pk0, pk1;
#pragma unroll
        for (int r = 0; r < 4; ++r) {
            p0[r] = __expf(p0[r] - m_run);
            p1[r] = __expf(p1[r] - m_run);
            ps += p0[r] + p1[r];
            pk0[r] = (bf16)p0[r];
            pk1[r] = (bf16)p1[r];
        }
        ps += __shfl_xor(ps, 16);
        ps += __shfl_xor(ps, 32);
        l_run += ps;

        *(bf16x4*)(pwr + ((lg * 8) ^ kx)) = pk0;
        *(bf16x4*)(pwr + ((32 + lg * 8) ^ kx)) = pk1;
        asm volatile("s_waitcnt lgkmcnt(0)" ::: "memory");
        __builtin_amdgcn_sched_barrier(0x20);
        bf16x8 py = *(bf16x8*)(Pb + w * 1024 + lr * 64 + ((lg * 16) ^ kx));
        __builtin_amdgcn_s_setprio(1);
        oacc[0] = __builtin_amdgcn_mfma_f32_16x16x32_bf16(vx0, py, oacc[0], 0, 0, 0);
        oacc[1] = __builtin_amdgcn_mfma_f32_16x16x32_bf16(vx1, py, oacc[1], 0, 0, 0);
        oacc[2] = __builtin_amdgcn_mfma_f32_16x16x32_bf16(vx2, py, oacc[2], 0, 0, 0);
        oacc[3] = __builtin_amdgcn_mfma_f32_16x16x32_bf16(vx3, py, oacc[3], 0, 0, 0);
        __builtin_amdgcn_s_setprio(0);
    }

    __syncthreads();
    if (lg == 0) { Msh[ti][s][lr] = m_run; Lsh[ti][s][lr] = l_run; }
    __syncthreads();
    float m0 = Msh[ti][0][lr], m1 = Msh[ti][1][lr], m2 = Msh[ti][2][lr], m3 = Msh[ti][3][lr];
    float mtot = fmaxf(fmaxf(m0, m1), fmaxf(m2, m3));
    float l_tot = Lsh[ti][0][lr] * __expf(m0 - mtot) + Lsh[ti][1][lr] * __expf(m1 - mtot)
                + Lsh[ti][2][lr] * __expf(m2 - mtot) + Lsh[ti][3][lr] * __expf(m3 - mtot);
    float fac = __expf(m_run - mtot);
#pragma unroll
    for (int d = 0; d < 4; ++d) oacc[d] *= fac;
    if (s == 0) {
#pragma unroll
        for (int db = 0; db < 4; ++db)
#pragma unroll
            for (int r = 0; r < 4; ++r) Osh[ti][db * 16 + lg * 4 + r][lr] = oacc[db][r];
    }
    __syncthreads();
    if (s == 1) {
#pragma unroll
        for (int db = 0; db < 4; ++db)
#pragma unroll
            for (int r = 0; r < 4; ++r) Osh[ti][db * 16 + lg * 4 + r][lr] += oacc[db][r];
    }
    __syncthreads();
    if (s == 2) {
#pragma unroll
        for (int db = 0; db < 4; ++db)
#pragma unroll
            for (int r = 0; r < 4; ++r) Osh[ti][db * 16 + lg * 4 + r][lr] += oacc[db][r];
    }
    __syncthreads();
    if (s == 3) {
        float inv = 1.f / l_tot;
#pragma unroll
        for (int db = 0; db < 4; ++db) {
            bf16x4 o4;
#pragma unroll
            for (int r = 0; r < 4; ++r)
                o4[r] = (bf16)((Osh[ti][db * 16 + lg * 4 + r][lr] + oacc[db][r]) * inv);
            *(bf16x4*)(ob + (size_t)(irow + lr) * HDIM + hh * DK + db * 16 + lg * 4) = o4;
        }
    }
}

// ---------------- f32 GEMM (final 512->64 projection only) ----------------
__global__ __launch_bounds__(256) void k_gemm(const float* __restrict__ A, const float* __restrict__ B,
                                              const float* __restrict__ bvec, float* __restrict__ C,
                                              int M, int Nc, int K) {
    __shared__ float As[16][68];
    __shared__ float Bs[16][68];
    int t = threadIdx.x;
    int tm = t >> 4, tn = t & 15;
    int i0 = blockIdx.y * 64, j0 = blockIdx.x * 64;
    int ar = t >> 2, aq = t & 3;
    int br = t >> 4, bq = t & 15;
    float acc[4][4] = {};
    for (int k0 = 0; k0 < K; k0 += 16) {
        float4 av = *(const float4*)(A + (size_t)(i0 + ar) * K + k0 + aq * 4);
        As[aq * 4 + 0][ar] = av.x;
        As[aq * 4 + 1][ar] = av.y;
        As[aq * 4 + 2][ar] = av.z;
        As[aq * 4 + 3][ar] = av.w;
        *(float4*)&Bs[br][bq * 4] = *(const float4*)(B + (size_t)(k0 + br) * Nc + j0 + bq * 4);
        __syncthreads();
#pragma unroll
        for (int k = 0; k < 16; ++k) {
            float4 a4 = *(const float4*)&As[k][tm * 4];
            float4 b4 = *(const float4*)&Bs[k][tn * 4];
            float avv[4] = {a4.x, a4.y, a4.z, a4.w};
            float bvv[4] = {b4.x, b4.y, b4.z, b4.w};
#pragma unroll
            for (int r = 0; r < 4; ++r)
#pragma unroll
                for (int c = 0; c < 4; ++c) acc[r][c] += avv[r] * bvv[c];
        }
        __syncthreads();
    }
#pragma unroll
    for (int r = 0; r < 4; ++r) {
#pragma unroll
        for (int c = 0; c < 4; ++c) {
            int i = i0 + tm * 4 + r;
            int j = j0 + tn * 4 + c;
            C[(size_t)i * Nc + j] = acc[r][c] + bvec[j];
        }
    }
}

extern "C" void kernel_launch(void* const* d_in, const int* in_sizes, int n_in,
                              void* d_out, int out_size, void* d_ws, size_t ws_size,
                              hipStream_t stream) {
    const float* x      = (const float*)d_in[0];
    const int*   ei     = (const int*)d_in[1];
    const float* eattr  = (const float*)d_in[2];
    const int*   epaths = (const int*)d_in[4];
    const float* Wn     = (const float*)d_in[5];
    const float* bn     = (const float*)d_in[6];
    const float* We     = (const float*)d_in[7];
    const float* be     = (const float*)d_in[8];
    const float* zin    = (const float*)d_in[9];
    const float* zout   = (const float*)d_in[10];
    const float* bsp    = (const float*)d_in[11];
    const float* ev     = (const float*)d_in[12];
    const float* ln1s   = (const float*)d_in[13];
    const float* ln1b   = (const float*)d_in[14];
    const float* Wq     = (const float*)d_in[15];
    const float* bq     = (const float*)d_in[16];
    const float* Wk     = (const float*)d_in[17];
    const float* bk     = (const float*)d_in[18];
    const float* Wv     = (const float*)d_in[19];
    const float* bv     = (const float*)d_in[20];
    const float* Wo     = (const float*)d_in[21];
    const float* bo     = (const float*)d_in[22];
    const float* ln2s   = (const float*)d_in[23];
    const float* ln2b   = (const float*)d_in[24];
    const float* W1     = (const float*)d_in[25];
    const float* b1     = (const float*)d_in[26];
    const float* W2     = (const float*)d_in[27];
    const float* b2     = (const float*)d_in[28];
    const float* Wout   = (const float*)d_in[29];
    const float* bout   = (const float*)d_in[30];

    char* base = (char*)d_ws;
    size_t off = 0;
    auto alloc = [&](size_t bytes) { char* p = base + off; off = (off + bytes + 255) & ~(size_t)255; return p; };
    bf16*  bias   = (bf16*)alloc((size_t)N_NODES * N_NODES * 2);
    float* h      = (float*)alloc((size_t)N_NODES * HDIM * 4);
    bf16*  wT     = (bf16*)alloc((size_t)LPATH * NEDGE * 2);
    float* Mb     = (float*)alloc(96 * 4);
    float* c5     = (float*)alloc(16 * 4);
    int*   deg    = (int*)alloc(2 * N_NODES * 4);
    bf16*  xbf    = (bf16*)alloc((size_t)N_NODES * FDIM * 2);
    bf16*  WnT    = (bf16*)alloc((size_t)HDIM * FDIM * 2);
    // overlaid region: (idx planes + mask) during bias passes, then Wt + activations
    char*  region = alloc(26u * 1024 * 1024);
    u16*   idxp   = (u16*)region;
    unsigned char* maskp = (unsigned char*)(region + (size_t)LPATH * PHALF * 2);
    bf16*  Wt     = (bf16*)region;
    bf16*  y_bf   = Wt + (size_t)NLAYER * 6 * HDIM * HDIM;
    bf16*  qfb    = y_bf + (size_t)N_NODES * HDIM;
    bf16*  kfb    = qfb + (size_t)N_NODES * HDIM / 2 * 2;   // NHEAD*128*2*512 = N*HDIM... (1M elems)
    bf16*  vfb    = kfb + (size_t)NHEAD * 128 * 2 * 512;
    bf16*  ob_bf  = vfb + (size_t)NHEAD * 4 * 64 * 512;
    bf16*  t1_bf  = ob_bf + (size_t)N_NODES * HDIM;
    int* din = deg;
    int* dout = deg + N_NODES;

    hipMemsetAsync(deg, 0, 2 * N_NODES * sizeof(int), stream);

    k_edge_mat<<<1, 128, 0, stream>>>(We, be, ev, Mb, c5);
    k_edge_w<<<NEDGE / 256, 256, 0, stream>>>(eattr, Mb, c5, wT);
    k_deg<<<NEDGE / 256, 256, 0, stream>>>(ei, din, dout);

    // bias: two half-passes (idx buffers overlay the Wt region, consumed before k_wprep)
    for (int half = 0; half < 2; ++half) {
        k_pack<<<PHALF / 1024, 256, 0, stream>>>(epaths + (size_t)half * PHALF * 5, idxp, maskp);
        k_bias2<<<256, 1024, 0, stream>>>(idxp, maskp, wT, bsp, bias + (size_t)half * PHALF);
    }

    k_wprep<<<dim3(64, 24), 256, 0, stream>>>(Wq, Wk, Wv, Wo, W1, W2, Wt);
    k_wprepn<<<16, 256, 0, stream>>>(Wn, WnT);
    k_xcast<<<(N_NODES * FDIM) / 1024, 256, 0, stream>>>(x, xbf);
    k_nmm<<<dim3(8, 32), 256, 0, stream>>>(xbf, WnT, bn, zin, zout, din, dout, h);

    dim3 gqkv(48, 32);
    dim3 gmm(8, 32);

    for (int lay = 0; lay < NLAYER; ++lay) {
        const bf16* Wt_l = Wt + (size_t)lay * 6 * HDIM * HDIM;
        size_t bOff = (size_t)lay * HDIM;
        k_ln<<<N_NODES, 256, 0, stream>>>(h, ln1s + bOff, ln1b + bOff, y_bf);
        k_qkv<<<gqkv, 256, 0, stream>>>(y_bf, Wt_l, bq + bOff, bk + bOff, bv + bOff, qfb, kfb, vfb);
        k_attn2<<<256, 1024, 0, stream>>>(qfb, kfb, vfb, bias, ob_bf);
        k_mm<<<gmm, 1024, 0, stream>>>(ob_bf, Wt_l + (size_t)3 * HDIM * HDIM, bo + bOff, h, h, nullptr, FL_RES | FL_OUTF);
        k_ln<<<N_NODES, 256, 0, stream>>>(h, ln2s + bOff, ln2b + bOff, y_bf);
        k_mm<<<gmm, 1024, 0, stream>>>(y_bf, Wt_l + (size_t)4 * HDIM * HDIM, b1 + bOff, nullptr, nullptr, t1_bf, FL_GELU);
        k_mm<<<gmm, 1024, 0, stream>>>(t1_bf, Wt_l + (size_t)5 * HDIM * HDIM, b2 + bOff, h, h, nullptr, FL_RES | FL_OUTF);
    }
    k_gemm<<<dim3(1, 32), 256, 0, stream>>>(h, Wout, bout, (float*)d_out, N_NODES, ODIM, HDIM);
}